// Round 13
// baseline (331.486 us; speedup 1.0000x reference)
//
#include <hip/hip_runtime.h>
#include <hip/hip_fp16.h>

#define WAVE 64
#define NXCD 8
#define NRMAX 200
#define RSTRIDE 17      // float4 units: 272B row stride -> per-rel start-bank offset 4*(rel%8)
#define HOP_TPB 1024
#define HOP_BLOCKS 512
#define CSR_BLOCKS 2048
#define CSR_TPB 256
#define CAP 16          // slots per entity; P(Poisson(5)>16)~1.4e-5 -> ~3 ovf triples/run
#define OVF_CAP 32768

typedef int v4i __attribute__((ext_vector_type(4)));

// ---- prologue: transpose (blocks [0,tgrid)) + split-K compute_r (next 608)
// + cnt/novf zeroing (rest). R20: prologue was 54.6us at 1TB/s, occ 35% --
// (a) transpose had 4B scalar loads/stores (256B/wave, 1/4 sweet spot);
// (b) compute_r had a 300-load serial K-chain on 160 blocks (0.6/CU tail).
// Fix: float4 loads + uint4 stores (1KB/wave each); split-K=4 + shfl reduce
// (critical path 75, 608 blocks).
// R11 lesson: do NOT fuse the scatter in here (L2 interference +27us).
__global__ void prologue_kernel(const float* __restrict__ x, const float* __restrict__ q,
                                const float* __restrict__ W1, const float* __restrict__ b1,
                                const float* __restrict__ W2, const float* __restrict__ b2,
                                const float* __restrict__ W3, const float* __restrict__ b3,
                                float* __restrict__ rT, __half2* __restrict__ xT,
                                int* __restrict__ cnt, int N_E, int N_R, int N_W2V,
                                int tgrid, int nrx, int rblocks, int zcount) {
    __shared__ float tile[64][65];
    int bid = blockIdx.x;
    if (bid < tgrid) {
        // x (B=64, N_E) fp32 -> xT (N_E, 64) fp16. tile written [batch][entity];
        // readout picks batch pairs from tile[b][ei] (R3 bug was the swap).
        int e0 = bid * 64;
        int li  = threadIdx.x & 63;
        int wv4 = threadIdx.x >> 6;              // 0..3
        #pragma unroll
        for (int it = 0; it < 4; ++it) {
            int b  = it * 16 + wv4 * 4 + (li >> 4);   // 0..63, unique per (it,wv4,li>>4)
            int ch = li & 15;                          // float4 chunk within 64-entity row
            int e  = e0 + ch * 4;
            float4 v = make_float4(0.f, 0.f, 0.f, 0.f);
            if (e < N_E) v = *(const float4*)(x + (size_t)b * N_E + e);   // 16B/lane, 1KB/wave
            tile[b][ch * 4 + 0] = v.x;
            tile[b][ch * 4 + 1] = v.y;
            tile[b][ch * 4 + 2] = v.z;
            tile[b][ch * 4 + 3] = v.w;
        }
        __syncthreads();
        #pragma unroll
        for (int it = 0; it < 2; ++it) {
            int i  = it * 256 + threadIdx.x;     // 0..511
            int jq = i & 7;                      // uint4 index within entity row (8x16B = 128B)
            int ei = i >> 3;                     // entity 0..63
            int e  = e0 + ei;
            if (e < N_E) {
                __half2 h[4];
                #pragma unroll
                for (int r = 0; r < 4; ++r)
                    h[r] = __floats2half2_rn(tile[jq * 8 + 2 * r][ei], tile[jq * 8 + 2 * r + 1][ei]);
                uint4 vv = make_uint4(*(unsigned*)&h[0], *(unsigned*)&h[1],
                                      *(unsigned*)&h[2], *(unsigned*)&h[3]);
                *(uint4*)((char*)xT + ((size_t)e * 64 + jq * 8) * 2) = vv;   // 1KB/wave contiguous
            }
        }
    } else if (bid < tgrid + rblocks) {
        // rT layout: [layer][N_R][64] (batch innermost). Split-K=4:
        // wave = 16 its x 4 K-chunks of 75; shfl_xor(16,32) reduce.
        int rb = bid - tgrid;
        int bx = rb % nrx;
        int by = rb / nrx;                        // 0..15
        int lane = threadIdx.x & 63;
        int wv   = threadIdx.x >> 6;
        int b    = by * 4 + wv;                   // batch 0..63
        int itl  = lane & 15;
        int kh   = lane >> 4;                     // 0..3
        int it   = bx * 16 + itl;
        float a = 0.f;
        int l = 0, j = 0;
        if (it < 3 * N_R) {
            l = it / N_R;
            j = it - l * N_R;
            const float* W    = (l == 0) ? W1 : (l == 1) ? W2 : W3;
            const float* qrow = q + (size_t)b * N_W2V;
            int kq = N_W2V >> 2;                  // 75
            int k0 = kh * kq;
            int k1 = (kh == 3) ? N_W2V : k0 + kq;
            for (int k = k0; k < k1; ++k)
                a = fmaf(qrow[k], W[(size_t)k * N_R + j], a);
        }
        a += __shfl_xor(a, 16);                   // kh0<->kh1, kh2<->kh3
        a += __shfl_xor(a, 32);                   // (01)<->(23)
        if (it < 3 * N_R && kh == 0) {
            const float* bv = (l == 0) ? b1 : (l == 1) ? b2 : b3;
            rT[(size_t)it * WAVE + b] = bv[j] + a;
        }
    } else {
        // zero cnt + novf: (N_E+4) ints = zcount int4's exactly (N_E=200000)
        int zb = bid - tgrid - rblocks;
        int i4 = zb * 256 + threadIdx.x;
        if (i4 < zcount) ((v4i*)cnt)[i4] = (v4i){0, 0, 0, 0};
    }
}

// ---- bucket build (R14/R6 exact form, measured 53.7us standalone) ----
// R5: XCD group only touches its own entity slice. One fixed-capacity
// atomic pass; ~50us is the device floor for 1M random device-scope
// atomics (R16/R17: three structures all 42-58us; ILP restructure and
// partition both regressed).
__global__ void scatter_direct_kernel(const int* __restrict__ subj, const int* __restrict__ rel,
                                      const int* __restrict__ obj,
                                      int* __restrict__ cnt, unsigned* __restrict__ slots,
                                      int* __restrict__ novf, int* __restrict__ ovf_obj,
                                      unsigned* __restrict__ ovf_pk, int nT, int nE) {
    int grp = blockIdx.x & (NXCD - 1);
    int sh  = (nE + NXCD - 1) / NXCD;
    int lo  = grp * sh;
    int hi  = min(nE, lo + sh);
    int tid    = (blockIdx.x >> 3) * blockDim.x + threadIdx.x;
    int stride = (gridDim.x >> 3) * blockDim.x;
    int nT4 = nT >> 2;
    const v4i* obj4 = (const v4i*)obj;
    for (int t = tid; t < nT4; t += stride) {
        v4i o = obj4[t];
        int base = t * 4;
        #pragma unroll
        for (int u = 0; u < 4; ++u) {
            int oo = o[u];
            if (oo >= lo && oo < hi) {
                unsigned pk = (unsigned)subj[base + u] | ((unsigned)rel[base + u] << 18);
                int slot = atomicAdd(&cnt[oo], 1);
                if (slot < CAP) slots[(size_t)oo * CAP + slot] = pk;
                else {
                    int oi = atomicAdd(novf, 1);
                    if (oi < OVF_CAP) { ovf_obj[oi] = oo; ovf_pk[oi] = pk; }
                }
            }
        }
    }
    for (int t = nT4 * 4 + tid; t < nT; t += stride) {
        int oo = obj[t];
        if (oo >= lo && oo < hi) {
            unsigned pk = (unsigned)subj[t] | ((unsigned)rel[t] << 18);
            int slot = atomicAdd(&cnt[oo], 1);
            if (slot < CAP) slots[(size_t)oo * CAP + slot] = pk;
            else {
                int oi = atomicAdd(novf, 1);
                if (oi < OVF_CAP) { ovf_obj[oi] = oo; ovf_pk[oi] = pk; }
            }
        }
    }
}

// ---- hops ----
// R10: fp16 intermediates. R12: fp16 x0 + unroll-8 issue-early gathers.
// R13: gather FETCH matches the distinct-line floor -> random-access-BW
// bound (~3.5TB/s). R18: overflow merged INLINE (same-block compute, no
// cross-phase coherence); deleted 3 ovf dispatches.

__device__ __forceinline__ float4 h4_to_f4(uint2 v) {
    float2 f0 = __half22float2(*(__half2*)&v.x);
    float2 f1 = __half22float2(*(__half2*)&v.y);
    return make_float4(f0.x, f0.y, f1.x, f1.y);
}

__device__ __forceinline__ uint2 pack_half4(float4 a) {
    __half2 h0 = __floats2half2_rn(a.x, a.y);
    __half2 h1 = __floats2half2_rn(a.z, a.w);
    uint2 v;
    v.x = *(unsigned*)&h0;
    v.y = *(unsigned*)&h1;
    return v;
}

// 4 entities/wave, 16 lanes x uint2 (8B) per fp16 entity row.
__device__ __forceinline__ float4 hop_accum4(const uint2* __restrict__ xp,
                                             const float4* __restrict__ r_lds,
                                             const int* __restrict__ cnt,
                                             const unsigned* __restrict__ slots,
                                             const int* __restrict__ novf,
                                             const int* __restrict__ ovf_obj,
                                             const unsigned* __restrict__ ovf_pk,
                                             int e, int g, int c, int nE) {
    float4 acc = make_float4(0.f, 0.f, 0.f, 0.f);
    int lraw = (e < nE) ? cnt[e] : 0;
    int len = min(lraw, CAP);
    unsigned pv = (c < len) ? slots[(size_t)e * CAP + c] : 0u;  // whole bucket = one 64B line
    int m = max(len, __shfl_xor(len, 16));            // wave-max over the 4 groups
    m = max(m, __shfl_xor(m, 32));
    for (int j0 = 0; j0 < m; j0 += 8) {
        uint2 xv[8];
        unsigned pr[8];
        #pragma unroll
        for (int u = 0; u < 8; ++u) {                 // issue all 8 gathers first
            int jj = max(min(j0 + u, len - 1), 0);    // clamp: dup loads hit hot lines
            unsigned p = __shfl(pv, (g << 4) + jj);   // per-lane src index: group-local broadcast
            pr[u] = p >> 18;
            xv[u] = xp[(size_t)(p & 0x3FFFFu) * 16 + c];
        }
        #pragma unroll
        for (int u = 0; u < 8; ++u) {                 // consume with LDS-r FMAs
            if (j0 + u < len) {
                float4 rv = r_lds[pr[u] * RSTRIDE + c];
                float4 xf = h4_to_f4(xv[u]);
                acc.x = fmaf(xf.x, rv.x, acc.x);
                acc.y = fmaf(xf.y, rv.y, acc.y);
                acc.z = fmaf(xf.z, rv.z, acc.z);
                acc.w = fmaf(xf.w, rv.w, acc.w);
            }
        }
    }
    if (__any(lraw > CAP)) {                          // rare (~3 entities/run)
        if (lraw > CAP) {
            int n = min(*novf, OVF_CAP);
            for (int i = 0; i < n; ++i) {
                if (ovf_obj[i] == e) {
                    unsigned p = ovf_pk[i];
                    float4 xf = h4_to_f4(xp[(size_t)(p & 0x3FFFFu) * 16 + c]);
                    float4 rv = r_lds[(p >> 18) * RSTRIDE + c];
                    acc.x = fmaf(xf.x, rv.x, acc.x);
                    acc.y = fmaf(xf.y, rv.y, acc.y);
                    acc.z = fmaf(xf.z, rv.z, acc.z);
                    acc.w = fmaf(xf.w, rv.w, acc.w);
                }
            }
        }
    }
    return acc;
}

// hops 1-2: 1024-thread blocks (16 waves x 4 entities = 64-entity tiles),
// grid-stride, 512 resident blocks (2/CU, 32 waves/CU). fp16 in, fp16 out.
__global__ __launch_bounds__(HOP_TPB, 8)
void hop_mid_kernel(const uint2* __restrict__ xp, const float4* __restrict__ rT4,
                    const int* __restrict__ cnt, const unsigned* __restrict__ slots,
                    const int* __restrict__ novf, const int* __restrict__ ovf_obj,
                    const unsigned* __restrict__ ovf_pk,
                    uint2* __restrict__ yh, int nE, int nR) {
    __shared__ float4 r_lds[NRMAX * RSTRIDE];
    for (int i = threadIdx.x; i < nR * 16; i += HOP_TPB)
        r_lds[(i >> 4) * RSTRIDE + (i & 15)] = rT4[i];
    __syncthreads();
    int lane = threadIdx.x & 63;
    int g = lane >> 4, c = lane & 15;
    int wv = threadIdx.x >> 6;                   // 0..15
    int nTiles = (nE + 63) >> 6;
    for (int t = blockIdx.x; t < nTiles; t += gridDim.x) {
        int e = t * 64 + wv * 4 + g;
        float4 acc = hop_accum4(xp, r_lds, cnt, slots, novf, ovf_obj, ovf_pk, e, g, c, nE);
        if (e < nE) yh[(size_t)e * 16 + c] = pack_half4(acc);
    }
}

// hop 3 fused with output transpose: 64-entity LDS tile, stores (B, N_E) fp32.
__global__ __launch_bounds__(HOP_TPB, 8)
void hop_out_kernel(const uint2* __restrict__ xp, const float4* __restrict__ rT4,
                    const int* __restrict__ cnt, const unsigned* __restrict__ slots,
                    const int* __restrict__ novf, const int* __restrict__ ovf_obj,
                    const unsigned* __restrict__ ovf_pk,
                    float* __restrict__ out, int nE, int nR) {
    __shared__ float4 r_lds[NRMAX * RSTRIDE];
    __shared__ float tile[64][65];
    for (int i = threadIdx.x; i < nR * 16; i += HOP_TPB)
        r_lds[(i >> 4) * RSTRIDE + (i & 15)] = rT4[i];
    __syncthreads();
    int lane = threadIdx.x & 63;
    int g = lane >> 4, c = lane & 15;
    int wv = threadIdx.x >> 6;                   // 0..15
    int nTiles = (nE + 63) >> 6;
    for (int t = blockIdx.x; t < nTiles; t += gridDim.x) {
        int e0 = t * 64;
        int ei = wv * 4 + g;                     // 0..63 unique per (wv,g)
        float4 acc = hop_accum4(xp, r_lds, cnt, slots, novf, ovf_obj, ovf_pk, e0 + ei, g, c, nE);
        tile[ei][4 * c + 0] = acc.x;
        tile[ei][4 * c + 1] = acc.y;
        tile[ei][4 * c + 2] = acc.z;
        tile[ei][4 * c + 3] = acc.w;
        __syncthreads();
        #pragma unroll
        for (int k = 0; k < 4; ++k) {
            int b = wv * 4 + k;
            int e = e0 + lane;
            if (e < nE) out[(size_t)b * nE + e] = tile[lane][b];
        }
        __syncthreads();                         // tile reused next iteration
    }
}

extern "C" void kernel_launch(void* const* d_in, const int* in_sizes, int n_in,
                              void* d_out, int out_size, void* d_ws, size_t ws_size,
                              hipStream_t stream) {
    const float* x  = (const float*)d_in[0];
    const float* q  = (const float*)d_in[1];
    const float* W1 = (const float*)d_in[2];
    const float* b1 = (const float*)d_in[3];
    const float* W2 = (const float*)d_in[4];
    const float* b2 = (const float*)d_in[5];
    const float* W3 = (const float*)d_in[6];
    const float* b3 = (const float*)d_in[7];
    const int* subj = (const int*)d_in[8];
    const int* rel  = (const int*)d_in[9];
    const int* obj  = (const int*)d_in[10];
    // n_hop (d_in[11]) is the constant 3 per the reference; hops hardcoded.

    const int B     = 64;
    const int N_E   = in_sizes[0] / B;   // 200000
    const int N_W2V = in_sizes[1] / B;   // 300
    const int N_R   = in_sizes[3];       // 200
    const int N_T   = in_sizes[8];       // 1000000

    const size_t h16bytes = (size_t)N_E * B * sizeof(__half);   // 25.6MB per fp16 buffer

    // ws layout: [cnt nE][novf 4][ovf_obj][ovf_pk][slots nE*CAP][rT][X0 fp16][H1 fp16?]
    int*      cnt     = (int*)d_ws;
    int*      novf    = cnt + N_E;
    int*      ovf_obj = novf + 4;
    unsigned* ovf_pk  = (unsigned*)(ovf_obj + OVF_CAP);
    unsigned* slots   = ovf_pk + OVF_CAP;
    char*     rT_raw  = (char*)(slots + (size_t)N_E * CAP);
    float*    rT      = (float*)(((uintptr_t)rT_raw + 15) & ~(uintptr_t)15);
    char*     X0      = (char*)(rT + (size_t)3 * N_R * B);      // 16B-aligned
    size_t used = (size_t)(X0 - (char*)d_ws) + h16bytes;

    char* H1;
    if (ws_size >= used + h16bytes) {
        H1 = X0 + h16bytes;
        used += h16bytes;
    } else {
        H1 = (char*)d_out;   // 25.6MB scratch in the 51.2MB output; dead before hop3's write
    }
    char* H2 = X0;           // X0 dead after hop1

    // 1) prologue: transpose + split-K compute_r + cnt/novf zeroing (one dispatch)
    int tgrid   = (N_E + 63) / 64;               // 3125
    int nrx     = (3 * N_R + 15) / 16;           // 38
    int rblocks = nrx * (B / 4);                 // 608
    int zcount  = (N_E + 4) / 4;                 // 50001 int4 (N_E+4 divisible by 4)
    int zblocks = (zcount + 255) / 256;          // 196
    prologue_kernel<<<tgrid + rblocks + zblocks, 256, 0, stream>>>(
        x, q, W1, b1, W2, b2, W3, b3, rT, (__half2*)X0, cnt,
        N_E, N_R, N_W2V, tgrid, nrx, rblocks, zcount);

    // 2) bucket build: one XCD-sharded atomic pass (standalone: no L2
    //    interference from the transpose stream)
    scatter_direct_kernel<<<CSR_BLOCKS, CSR_TPB, 0, stream>>>(
        subj, rel, obj, cnt, slots, novf, ovf_obj, ovf_pk, N_T, N_E);

    // 3) three hops (overflow merged inline); hop3 fuses the output transpose
    int hblocks = tgrid < HOP_BLOCKS ? tgrid : HOP_BLOCKS;
    const float4* rT1 = (const float4*)rT;
    const float4* rT2 = (const float4*)(rT + (size_t)1 * N_R * B);
    const float4* rT3 = (const float4*)(rT + (size_t)2 * N_R * B);

    hop_mid_kernel<<<hblocks, HOP_TPB, 0, stream>>>(
        (const uint2*)X0, rT1, cnt, slots, novf, ovf_obj, ovf_pk, (uint2*)H1, N_E, N_R);
    hop_mid_kernel<<<hblocks, HOP_TPB, 0, stream>>>(
        (const uint2*)H1, rT2, cnt, slots, novf, ovf_obj, ovf_pk, (uint2*)H2, N_E, N_R);
    hop_out_kernel<<<hblocks, HOP_TPB, 0, stream>>>(
        (const uint2*)H2, rT3, cnt, slots, novf, ovf_obj, ovf_pk, (float*)d_out, N_E, N_R);
}